// Round 8
// baseline (95.836 us; speedup 1.0000x reference)
//
#include <hip/hip_runtime.h>
#include <math.h>

constexpr int B_ = 32, T_ = 512, F_ = 128, R_ = 32;
constexpr int OUT_STRIDE = B_ * R_ * F_;
constexpr int BLOCK = 512;             // 8 waves; lb(512,4) -> 2 blocks/CU = 4 waves/SIMD

__device__ __forceinline__ float exp2_fast(float v) { return __builtin_amdgcn_exp2f(v); }

// One block per (b, r-pair). Uniform-kappa fast path: f-independent weight
// table in LDS; hot loop = 32-t chunks, wave owns 4 t (R5 granularity),
// unconditional affine loads (padded t's have exact-zero weights), explicit
// register double-buffer so next iter's 8 global loads are in flight during
// current iter's FMAs.
__launch_bounds__(BLOCK, 4)
__global__ void gauss_pair3(const float* __restrict__ xh, const float* __restrict__ mk,
                            const float* __restrict__ tau, const float* __restrict__ logk,
                            float* __restrict__ out) {
    const int lin = blockIdx.x;
    const int xcd = lin & 7, idx = lin >> 3;     // all 16 r-pair blocks of a b on one XCD
    const int g = idx >> 4, rp = idx & 15;
    const int b = xcd + 8 * g;
    const int r0 = 2 * rp, r1 = r0 + 1;

    const int tid = threadIdx.x, lane = tid & 63, w = tid >> 6;   // w in 0..7

    __shared__ float4 w_s[T_];        // {lp_r0, hp_r0, lp_r1, hp_r1}, 8 KB
    __shared__ float  th_s[T_];       // slow path only, 2 KB
    __shared__ float  red[2][8][64];  // 4 KB

    for (int i = tid; i < 2 * 8 * 64; i += BLOCK) (&red[0][0][0])[i] = 0.f;

    // per-wave redundant scan of tau row
    const float* tb = tau + b * T_;
    float v[8]; float s = 0.f;
#pragma unroll
    for (int k = 0; k < 8; ++k) { s += tb[lane * 8 + k]; v[k] = s; }
    float x = s;
#pragma unroll
    for (int d = 1; d < 64; d <<= 1) { float y = __shfl_up(x, d, 64); if (lane >= d) x += y; }
    const float excl = x - s;
#pragma unroll
    for (int k = 0; k < 8; ++k) v[k] = (excl + v[k]) * (1.f / 3600.f);
    if (w == 0) {
#pragma unroll
        for (int k = 0; k < 8; ++k) th_s[lane * 8 + k] = v[k];
    }

    // uniformity: bitwise equality vs logk[0]
    const int f0 = 2 * lane;
    const float L2E = 1.4426950408889634f;
    const float lk0 = logk[0];
    const float lkx = logk[f0], lky = logk[f0 + 1];
    const bool uni = __all((lkx == lk0) && (lky == lk0));

    float kl2e;
    if (uni) {
        const float sp0 = fmaxf(lk0, 0.f) + log1pf(expf(-fabsf(lk0)));
        kl2e = sp0 * L2E;
    } else {
        const float spx = fmaxf(lkx, 0.f) + log1pf(expf(-fabsf(lkx)));
        const float spy = fmaxf(lky, 0.f) + log1pf(expf(-fabsf(lky)));
        float mn = fminf(spx, spy);
#pragma unroll
        for (int d = 1; d < 64; d <<= 1) mn = fminf(mn, __shfl_xor(mn, d, 64));
        kl2e = mn * L2E;
    }

    const float c0 = (float)((48.0 * r0) / 31.0);
    const float c1 = (float)((48.0 * r1) / 31.0);

    // union active range [Llo,Lhi): dropped terms < 2^-30 (aggregate < 5e-7)
    const float Rlam = sqrtf(30.f / kl2e);
    int p = 0;
#pragma unroll
    for (int k = 0; k < 8; ++k)
        p += (int)(v[k] < c0 - Rlam) + ((int)(v[k] < c1 + Rlam) << 16);
#pragma unroll
    for (int d = 1; d < 64; d <<= 1) p += __shfl_xor(p, d, 64);
    const int Llo = p & 0xffff, Lhi = p >> 16;

    // weight table: thread covers t = lane*8 + w (all 512 once, one exp2-pair)
    {
        const int t = lane * 8 + w;
        const float th = v[w];
        const float d0 = th - c0, d1 = th - c1;
        const float a0 = d0 * d0 * kl2e, a1 = d1 * d1 * kl2e;
        const float lp0 = a0 < 30.f ? exp2_fast(-a0) : 0.f;
        const float lp1 = a1 < 30.f ? exp2_fast(-a1) : 0.f;
        const float q0 = lp0 * lp0, q1 = lp1 * lp1;
        const float hp0 = ((q0 * q0) * (q0 * q0)) * q0;   // lp^10
        const float hp1 = ((q1 * q1) * (q1 * q1)) * q1;
        w_s[t] = make_float4(lp0, hp0, lp1, hp1);
    }
    __syncthreads();

    const float* xb = xh + (size_t)b * T_ * F_ + f0;
    const float* mb = mk + (size_t)b * T_ * F_ + f0;
    float aL[2][2] = {}, aS[2][2] = {}, aH[2][2] = {}, aG[2][2] = {};

    if (uni) {
        const int lo = Llo & ~31;
        const int hi = (Lhi + 31) & ~31;          // <= 512 (Lhi <= 512)
        const int myt = w * 4;                    // wave owns 4 consecutive t per chunk
        float2 xv[4], mv[4]; float4 wv[4];
        if (lo < hi) {
            const int t0 = lo + myt;
#pragma unroll
            for (int j = 0; j < 4; ++j) {
                xv[j] = *(const float2*)(xb + (size_t)(t0 + j) * F_);
                mv[j] = *(const float2*)(mb + (size_t)(t0 + j) * F_);
                wv[j] = w_s[t0 + j];
            }
        }
        for (int base = lo; base < hi; base += 32) {
            // prefetch next chunk (wave-uniform select keeps addresses in-bounds)
            const int tn = (base + 32 < hi) ? (base + 32 + myt) : (lo + myt);
            float2 xn[4], mn2[4]; float4 wn[4];
#pragma unroll
            for (int j = 0; j < 4; ++j) {
                xn[j]  = *(const float2*)(xb + (size_t)(tn + j) * F_);
                mn2[j] = *(const float2*)(mb + (size_t)(tn + j) * F_);
                wn[j]  = w_s[tn + j];
            }
#pragma unroll
            for (int j = 0; j < 4; ++j) {
                const float mxx = mv[j].x * xv[j].x, mxy = mv[j].y * xv[j].y;
                aL[0][0] = fmaf(wv[j].x, mv[j].x, aL[0][0]);
                aL[0][1] = fmaf(wv[j].x, mv[j].y, aL[0][1]);
                aS[0][0] = fmaf(wv[j].x, mxx,     aS[0][0]);
                aS[0][1] = fmaf(wv[j].x, mxy,     aS[0][1]);
                aH[0][0] = fmaf(wv[j].y, mv[j].x, aH[0][0]);
                aH[0][1] = fmaf(wv[j].y, mv[j].y, aH[0][1]);
                aG[0][0] = fmaf(wv[j].y, mxx,     aG[0][0]);
                aG[0][1] = fmaf(wv[j].y, mxy,     aG[0][1]);
                aL[1][0] = fmaf(wv[j].z, mv[j].x, aL[1][0]);
                aL[1][1] = fmaf(wv[j].z, mv[j].y, aL[1][1]);
                aS[1][0] = fmaf(wv[j].z, mxx,     aS[1][0]);
                aS[1][1] = fmaf(wv[j].z, mxy,     aS[1][1]);
                aH[1][0] = fmaf(wv[j].w, mv[j].x, aH[1][0]);
                aH[1][1] = fmaf(wv[j].w, mv[j].y, aH[1][1]);
                aG[1][0] = fmaf(wv[j].w, mxx,     aG[1][0]);
                aG[1][1] = fmaf(wv[j].w, mxy,     aG[1][1]);
            }
#pragma unroll
            for (int j = 0; j < 4; ++j) { xv[j] = xn[j]; mv[j] = mn2[j]; wv[j] = wn[j]; }
        }
    } else {
        // general path: per-lane kappa, clamped loads over [Llo,Lhi)
        const float spx = fmaxf(lkx, 0.f) + log1pf(expf(-fabsf(lkx)));
        const float spy = fmaxf(lky, 0.f) + log1pf(expf(-fabsf(lky)));
        const float nkx = -spx * L2E, nky = -spy * L2E;
        for (int base = Llo; base < Lhi; base += 32) {
            float2 xv[4], mv[4]; float thv[4];
#pragma unroll
            for (int j = 0; j < 4; ++j) {
                const int t = base + w * 4 + j;
                const int tt = t < Lhi ? t : Lhi - 1;
                xv[j] = *(const float2*)(xb + (size_t)tt * F_);
                float2 m = *(const float2*)(mb + (size_t)tt * F_);
                if (t >= Lhi) { m.x = 0.f; m.y = 0.f; }
                mv[j] = m; thv[j] = th_s[tt];
            }
#pragma unroll
            for (int j = 0; j < 4; ++j) {
                const float mxx = mv[j].x * xv[j].x, mxy = mv[j].y * xv[j].y;
#pragma unroll
                for (int rr = 0; rr < 2; ++rr) {
                    const float c = rr ? c1 : c0;
                    const float d = thv[j] - c, d2 = d * d;
                    const float ex = exp2_fast(d2 * nkx), ey = exp2_fast(d2 * nky);
                    const float ex2 = ex * ex, ex4 = ex2 * ex2, ex8 = ex4 * ex4;
                    const float ey2 = ey * ey, ey4 = ey2 * ey2, ey8 = ey4 * ey4;
                    const float exA = ex8 * ex2, eyA = ey8 * ey2;
                    aL[rr][0] = fmaf(ex,  mv[j].x, aL[rr][0]);
                    aL[rr][1] = fmaf(ey,  mv[j].y, aL[rr][1]);
                    aS[rr][0] = fmaf(ex,  mxx,     aS[rr][0]);
                    aS[rr][1] = fmaf(ey,  mxy,     aS[rr][1]);
                    aH[rr][0] = fmaf(exA, mv[j].x, aH[rr][0]);
                    aH[rr][1] = fmaf(eyA, mv[j].y, aH[rr][1]);
                    aG[rr][0] = fmaf(exA, mxx,     aG[rr][0]);
                    aG[rr][1] = fmaf(eyA, mxy,     aG[rr][1]);
                }
            }
        }
    }

#pragma unroll
    for (int rr = 0; rr < 2; ++rr) {
        atomicAdd(&red[rr][0][lane], aL[rr][0]); atomicAdd(&red[rr][1][lane], aL[rr][1]);
        atomicAdd(&red[rr][2][lane], aS[rr][0]); atomicAdd(&red[rr][3][lane], aS[rr][1]);
        atomicAdd(&red[rr][4][lane], aH[rr][0]); atomicAdd(&red[rr][5][lane], aH[rr][1]);
        atomicAdd(&red[rr][6][lane], aG[rr][0]); atomicAdd(&red[rr][7][lane], aG[rr][1]);
    }
    __syncthreads();

    if (tid < 256) {
        const int rr = tid >> 7, f = tid & 127, l = f >> 1, h = f & 1;
        const float lam = red[rr][0 + h][l], sig = red[rr][2 + h][l];
        const float hp  = red[rr][4 + h][l], gam = red[rr][6 + h][l];
        const int base = (b * R_ + r0 + rr) * F_ + f;
        out[base]                  = sig / fmaxf(lam, 1.f);
        out[OUT_STRIDE + base]     = lam;
        out[2 * OUT_STRIDE + base] = gam / fmaxf(hp, 1.f);
    }
}

extern "C" void kernel_launch(void* const* d_in, const int* in_sizes, int n_in,
                              void* d_out, int out_size, void* d_ws, size_t ws_size,
                              hipStream_t stream) {
    const float* x_hat = (const float*)d_in[0];
    const float* mask  = (const float*)d_in[1];
    const float* tau   = (const float*)d_in[2];
    const float* logk  = (const float*)d_in[3];
    float* out = (float*)d_out;

    gauss_pair3<<<B_ * (R_ / 2), BLOCK, 0, stream>>>(x_hat, mask, tau, logk, out);
}

// Round 9
// 86.519 us; speedup vs baseline: 1.1077x; 1.1077x over previous
//
#include <hip/hip_runtime.h>
#include <math.h>

constexpr int B_ = 32, T_ = 512, F_ = 128, R_ = 32;
constexpr int OUT_STRIDE = B_ * R_ * F_;

__device__ __forceinline__ float exp2_fast(float v) { return __builtin_amdgcn_exp2f(v); }

// R9 = R5 verbatim (best measured config: 87.0 us).
// One block per (b, r-pair), 256 threads (4 waves). Uniform-kappa fast path:
// f-independent weight table in LDS (one exp2-pair per t per r), hot loop is
// pure load+FMA with a single broadcast ds_read_b128 per t.
__launch_bounds__(256, 2)
__global__ void gauss_pair(const float* __restrict__ xh, const float* __restrict__ mk,
                           const float* __restrict__ tau, const float* __restrict__ logk,
                           float* __restrict__ out) {
    const int lin = blockIdx.x;
    const int xcd = lin & 7, idx = lin >> 3;     // idx 0..63
    const int g = idx >> 4;                      // 0..3
    const int rp = idx & 15;
    const int b = xcd + 8 * g;
    const int r0 = 2 * rp, r1 = r0 + 1;

    const int tid = threadIdx.x, lane = tid & 63, w = tid >> 6;

    __shared__ float4 w_s[T_];        // {lp_r0, hp_r0, lp_r1, hp_r1}, 8 KB
    __shared__ float  th_s[T_];       // slow path only
    __shared__ float  red[2][8][64];  // [r][acc*2+h][lane], 4 KB

    for (int i = tid; i < 2 * 8 * 64; i += 256) (&red[0][0][0])[i] = 0.f;

    const float* tb = tau + b * T_;
    float v[8]; float s = 0.f;
#pragma unroll
    for (int k = 0; k < 8; ++k) { s += tb[lane * 8 + k]; v[k] = s; }
    float x = s;
#pragma unroll
    for (int d = 1; d < 64; d <<= 1) { float y = __shfl_up(x, d, 64); if (lane >= d) x += y; }
    const float excl = x - s;
#pragma unroll
    for (int k = 0; k < 8; ++k) v[k] = (excl + v[k]) * (1.f / 3600.f);
    if (w == 0) {
#pragma unroll
        for (int k = 0; k < 8; ++k) th_s[lane * 8 + k] = v[k];
    }

    const int f0 = 2 * lane;
    const float L2E = 1.4426950408889634f;
    const float lkx = logk[f0], lky = logk[f0 + 1];
    const float spx = fmaxf(lkx, 0.f) + log1pf(expf(-fabsf(lkx)));
    const float spy = fmaxf(lky, 0.f) + log1pf(expf(-fabsf(lky)));
    float mn = fminf(spx, spy), mx = fmaxf(spx, spy);
#pragma unroll
    for (int d = 1; d < 64; d <<= 1) {
        mn = fminf(mn, __shfl_xor(mn, d, 64));
        mx = fmaxf(mx, __shfl_xor(mx, d, 64));
    }
    const bool uni = (mn == mx);
    const float kl2e = mn * L2E;
    const float nkx = -spx * L2E, nky = -spy * L2E;

    const float c0 = (float)((48.0 * r0) / 31.0);
    const float c1 = (float)((48.0 * r1) / 31.0);

    const float Rlam = sqrtf(30.f / kl2e);
    int p = 0;
#pragma unroll
    for (int k = 0; k < 8; ++k)
        p += (int)(v[k] < c0 - Rlam) + ((int)(v[k] < c1 + Rlam) << 16);
#pragma unroll
    for (int d = 1; d < 64; d <<= 1) p += __shfl_xor(p, d, 64);
    const int Llo = p & 0xffff, Lhi = p >> 16;

#pragma unroll
    for (int k = 0; k < 8; ++k) {
        if ((k >> 1) == w) {
            const int t = lane * 8 + k;
            const float th = v[k];
            const float d0 = th - c0, d1 = th - c1;
            const float a0 = d0 * d0 * kl2e, a1 = d1 * d1 * kl2e;
            const float lp0 = a0 < 30.f ? exp2_fast(-a0) : 0.f;
            const float lp1 = a1 < 30.f ? exp2_fast(-a1) : 0.f;
            const float q0 = lp0 * lp0, q1 = lp1 * lp1;
            const float hp0 = ((q0 * q0) * (q0 * q0)) * q0;
            const float hp1 = ((q1 * q1) * (q1 * q1)) * q1;
            w_s[t] = make_float4(lp0, hp0, lp1, hp1);
        }
    }
    __syncthreads();

    const float* xb = xh + (size_t)b * T_ * F_ + f0;
    const float* mb = mk + (size_t)b * T_ * F_ + f0;
    float aL[2][2] = {}, aS[2][2] = {}, aH[2][2] = {}, aG[2][2] = {};

    if (uni) {
        for (int base = Llo; base < Lhi; base += 16) {
            float2 xv[4], mv[4]; float4 wv[4];
#pragma unroll
            for (int j = 0; j < 4; ++j) {
                const int t = base + w * 4 + j;
                const int tt = t < Lhi ? t : Lhi - 1;
                xv[j] = *(const float2*)(xb + (size_t)tt * F_);
                float2 m = *(const float2*)(mb + (size_t)tt * F_);
                if (t >= Lhi) { m.x = 0.f; m.y = 0.f; }
                mv[j] = m;
                wv[j] = w_s[tt];
            }
#pragma unroll
            for (int j = 0; j < 4; ++j) {
                const float mxx = mv[j].x * xv[j].x, mxy = mv[j].y * xv[j].y;
                aL[0][0] = fmaf(wv[j].x, mv[j].x, aL[0][0]);
                aL[0][1] = fmaf(wv[j].x, mv[j].y, aL[0][1]);
                aS[0][0] = fmaf(wv[j].x, mxx,     aS[0][0]);
                aS[0][1] = fmaf(wv[j].x, mxy,     aS[0][1]);
                aH[0][0] = fmaf(wv[j].y, mv[j].x, aH[0][0]);
                aH[0][1] = fmaf(wv[j].y, mv[j].y, aH[0][1]);
                aG[0][0] = fmaf(wv[j].y, mxx,     aG[0][0]);
                aG[0][1] = fmaf(wv[j].y, mxy,     aG[0][1]);
                aL[1][0] = fmaf(wv[j].z, mv[j].x, aL[1][0]);
                aL[1][1] = fmaf(wv[j].z, mv[j].y, aL[1][1]);
                aS[1][0] = fmaf(wv[j].z, mxx,     aS[1][0]);
                aS[1][1] = fmaf(wv[j].z, mxy,     aS[1][1]);
                aH[1][0] = fmaf(wv[j].w, mv[j].x, aH[1][0]);
                aH[1][1] = fmaf(wv[j].w, mv[j].y, aH[1][1]);
                aG[1][0] = fmaf(wv[j].w, mxx,     aG[1][0]);
                aG[1][1] = fmaf(wv[j].w, mxy,     aG[1][1]);
            }
        }
    } else {
        for (int base = Llo; base < Lhi; base += 16) {
            float2 xv[4], mv[4]; float thv[4];
#pragma unroll
            for (int j = 0; j < 4; ++j) {
                const int t = base + w * 4 + j;
                const int tt = t < Lhi ? t : Lhi - 1;
                xv[j] = *(const float2*)(xb + (size_t)tt * F_);
                float2 m = *(const float2*)(mb + (size_t)tt * F_);
                if (t >= Lhi) { m.x = 0.f; m.y = 0.f; }
                mv[j] = m; thv[j] = th_s[tt];
            }
#pragma unroll
            for (int j = 0; j < 4; ++j) {
                const float mxx = mv[j].x * xv[j].x, mxy = mv[j].y * xv[j].y;
#pragma unroll
                for (int rr = 0; rr < 2; ++rr) {
                    const float c = rr ? c1 : c0;
                    const float d = thv[j] - c, d2 = d * d;
                    const float ex = exp2_fast(d2 * nkx), ey = exp2_fast(d2 * nky);
                    const float ex2 = ex * ex, ex4 = ex2 * ex2, ex8 = ex4 * ex4;
                    const float ey2 = ey * ey, ey4 = ey2 * ey2, ey8 = ey4 * ey4;
                    const float exA = ex8 * ex2, eyA = ey8 * ey2;
                    aL[rr][0] = fmaf(ex,  mv[j].x, aL[rr][0]);
                    aL[rr][1] = fmaf(ey,  mv[j].y, aL[rr][1]);
                    aS[rr][0] = fmaf(ex,  mxx,     aS[rr][0]);
                    aS[rr][1] = fmaf(ey,  mxy,     aS[rr][1]);
                    aH[rr][0] = fmaf(exA, mv[j].x, aH[rr][0]);
                    aH[rr][1] = fmaf(eyA, mv[j].y, aH[rr][1]);
                    aG[rr][0] = fmaf(exA, mxx,     aG[rr][0]);
                    aG[rr][1] = fmaf(eyA, mxy,     aG[rr][1]);
                }
            }
        }
    }

#pragma unroll
    for (int rr = 0; rr < 2; ++rr) {
        atomicAdd(&red[rr][0][lane], aL[rr][0]); atomicAdd(&red[rr][1][lane], aL[rr][1]);
        atomicAdd(&red[rr][2][lane], aS[rr][0]); atomicAdd(&red[rr][3][lane], aS[rr][1]);
        atomicAdd(&red[rr][4][lane], aH[rr][0]); atomicAdd(&red[rr][5][lane], aH[rr][1]);
        atomicAdd(&red[rr][6][lane], aG[rr][0]); atomicAdd(&red[rr][7][lane], aG[rr][1]);
    }
    __syncthreads();

    {
        const int rr = tid >> 7, f = tid & 127, l = f >> 1, h = f & 1;
        const float lam = red[rr][0 + h][l], sig = red[rr][2 + h][l];
        const float hp  = red[rr][4 + h][l], gam = red[rr][6 + h][l];
        const int base = (b * R_ + r0 + rr) * F_ + f;
        out[base]                  = sig / fmaxf(lam, 1.f);
        out[OUT_STRIDE + base]     = lam;
        out[2 * OUT_STRIDE + base] = gam / fmaxf(hp, 1.f);
    }
}

extern "C" void kernel_launch(void* const* d_in, const int* in_sizes, int n_in,
                              void* d_out, int out_size, void* d_ws, size_t ws_size,
                              hipStream_t stream) {
    const float* x_hat = (const float*)d_in[0];
    const float* mask  = (const float*)d_in[1];
    const float* tau   = (const float*)d_in[2];
    const float* logk  = (const float*)d_in[3];
    float* out = (float*)d_out;

    gauss_pair<<<B_ * (R_ / 2), 256, 0, stream>>>(x_hat, mask, tau, logk, out);
}